// Round 1
// baseline (8202.478 us; speedup 1.0000x reference)
//
#include <hip/hip_runtime.h>
#include <hip/hip_bf16.h>
#include <cmath>

typedef __attribute__((ext_vector_type(8))) short bf16x8;
typedef __attribute__((ext_vector_type(4))) float f32x4;

#define DEVI __device__ __forceinline__

DEVI float sigf(float x) { return 1.0f / (1.0f + __expf(-x)); }

// ---- problem constants
#define BATCH 1024
#define CODE  2048
#define RNN   512
#define NG    2048      // 4*RNN
#define TSTEPS 128
#define K1K   2560      // CODE + RNN
#define K2K   1024      // RNN + RNN
#define K3K   512
#define NO    2176      // att cols padded: 2048 att + ang + wid + 126 pad (17 tiles of 128)

// swizzled byte offset within a [rows][128B] LDS tile: kills the 128B-stride bank conflict
DEVI int swz(int row, int cb) { return row * 128 + (cb ^ ((row & 7) << 4)); }

// ---------------------------------------------------------------------------
// prologue kernels (run every launch; d_ws is re-poisoned before each launch)
// ---------------------------------------------------------------------------

// W1T[np][k], np = 4u+g (gate-interleaved), k in [0,2560): rows 0..2047 = w_ih1, rest w_hh1
__global__ void conv_w1(const float* __restrict__ w_ih1, const float* __restrict__ w_hh1,
                        __hip_bfloat16* __restrict__ W1T) {
  int np = blockIdx.x;                       // 0..2047
  int co = (np & 3) * RNN + (np >> 2);       // original gate column
  for (int k = threadIdx.x; k < K1K; k += 256) {
    float v = (k < CODE) ? w_ih1[(size_t)k * NG + co]
                         : w_hh1[(size_t)(k - CODE) * NG + co];
    W1T[(size_t)np * K1K + k] = __float2bfloat16(v);
  }
}

__global__ void conv_w2(const float* __restrict__ w_ih2, const float* __restrict__ w_hh2,
                        __hip_bfloat16* __restrict__ W2T) {
  int np = blockIdx.x;
  int co = (np & 3) * RNN + (np >> 2);
  for (int k = threadIdx.x; k < K2K; k += 256) {
    float v = (k < RNN) ? w_ih2[(size_t)k * NG + co]
                        : w_hh2[(size_t)(k - RNN) * NG + co];
    W2T[(size_t)np * K2K + k] = __float2bfloat16(v);
  }
}

// WoT[n][k]: n<2048 att col n; n==2048 angles; n==2049 widths; else zero pad
__global__ void conv_wo(const float* __restrict__ w_att, const float* __restrict__ w_ang,
                        const float* __restrict__ w_wid, __hip_bfloat16* __restrict__ WoT) {
  int n = blockIdx.x;  // 0..2175
  for (int k = threadIdx.x; k < K3K; k += 256) {
    float v = 0.f;
    if (n < CODE) v = w_att[(size_t)k * CODE + n];
    else if (n == CODE) v = w_ang[k];
    else if (n == CODE + 1) v = w_wid[k];
    WoT[(size_t)n * K3K + k] = __float2bfloat16(v);
  }
}

__global__ void conv_b(const float* b_ih1, const float* b_hh1,
                       const float* b_ih2, const float* b_hh2,
                       const float* b_att, const float* b_ang, const float* b_wid,
                       float* b1p, float* b2p, float* bo) {
  int i = blockIdx.x * 256 + threadIdx.x;
  if (i < NG) {
    int co = (i & 3) * RNN + (i >> 2);
    b1p[i] = b_ih1[co] + b_hh1[co];
    b2p[i] = b_ih2[co] + b_hh2[co];
  }
  if (i < NO) {
    float v = 0.f;
    if (i < CODE) v = b_att[i];
    else if (i == CODE) v = b_ang[0];
    else if (i == CODE + 1) v = b_wid[0];
    bo[i] = v;
  }
}

// zero h_cat(2MB)+c1(2MB)+c2(2MB) contiguous + the h1 strip of x_bf
__global__ void init_zero(char* __restrict__ zb, char* __restrict__ xb) {
  int idx = blockIdx.x * 256 + threadIdx.x;       // grid 1024*256 = 262144
  f32x4 z = {0.f, 0.f, 0.f, 0.f};
  for (int i = idx; i < 393216; i += 262144) *(f32x4*)(zb + (size_t)i * 16) = z;
  for (int i = idx; i < 65536; i += 262144) {
    int row = i >> 6, j = i & 63;
    *(f32x4*)(xb + (size_t)row * (K1K * 2) + CODE * 2 + (size_t)j * 16) = z;
  }
}

// idea = tanh(latent @ w_unpack + b); also x_bf[:,0:2048] = idea (att0 = 1)
__global__ void idea_kernel(const float* __restrict__ latent, const float* __restrict__ w,
                            const float* __restrict__ b,
                            __hip_bfloat16* __restrict__ idea_bf,
                            __hip_bfloat16* __restrict__ x_bf) {
  int idx = blockIdx.x * 256 + threadIdx.x;       // grid 8192 -> 2M = 1024*2048
  int bi = idx >> 11, j = idx & 2047;
  const float* lr = latent + bi * 128;
  float s = b[j];
#pragma unroll 8
  for (int k = 0; k < 128; ++k) s = fmaf(lr[k], w[(size_t)k * CODE + j], s);
  __hip_bfloat16 h = __float2bfloat16(tanhf(s));
  idea_bf[idx] = h;
  x_bf[(size_t)bi * K1K + j] = h;
}

// ---------------------------------------------------------------------------
// fused GEMM + LSTM cell: C = A[M=1024,K] @ BT[N=2048,K]^T, gate-interleaved N.
// BM=64, BN=128, BK=64; 4 waves (2 row-halves x 2 col-halves), wave tile 32x64.
// Epilogue: gates -> LDS f32 recombine -> cell -> c_state(f32), h_out(bf16).
// ---------------------------------------------------------------------------
__global__ void __launch_bounds__(256)
lstm_gemm(const char* __restrict__ Ab, const char* __restrict__ Bb,
          int K, int nk, const float* __restrict__ bias,
          float* __restrict__ c_state, __hip_bfloat16* __restrict__ h_out, int h_ld) {
  __shared__ char smem[32768]; // A[64][64]bf16 @0 (swz), B[128][64]bf16 @8192 (swz); epi: f32[64][128]
  const int tid = threadIdx.x;
  const int m0 = blockIdx.x * 64;
  const int n0 = blockIdx.y * 128;
  const int kb = K * 2;  // row stride bytes (A rows and BT rows are both length K)

  const char* sA[2]; int dA[2];
  const char* sB[4]; int dB[4];
#pragma unroll
  for (int j = 0; j < 2; ++j) {
    int o = tid * 16 + j * 4096;
    int r = o >> 7, cb = o & 127;
    sA[j] = Ab + (size_t)(m0 + r) * kb + cb;
    dA[j] = swz(r, cb);
  }
#pragma unroll
  for (int j = 0; j < 4; ++j) {
    int o = tid * 16 + j * 4096;
    int r = o >> 7, cb = o & 127;
    sB[j] = Bb + (size_t)(n0 + r) * kb + cb;
    dB[j] = 8192 + swz(r, cb);
  }
  f32x4 ra[2], rb[4];
#pragma unroll
  for (int j = 0; j < 2; ++j) ra[j] = *(const f32x4*)sA[j];
#pragma unroll
  for (int j = 0; j < 4; ++j) rb[j] = *(const f32x4*)sB[j];

  const int lane = tid & 63, l16 = lane & 15, lg = lane >> 4;
  const int wv = tid >> 6, wr = wv & 1, wc = wv >> 1;
  const int xm = (l16 & 7) << 4;

  int aoff[2][2], boff[4][2];
#pragma unroll
  for (int fm = 0; fm < 2; ++fm) {
    int r = wr * 32 + fm * 16 + l16;
#pragma unroll
    for (int kk = 0; kk < 2; ++kk) aoff[fm][kk] = r * 128 + ((kk * 64 + lg * 16) ^ xm);
  }
#pragma unroll
  for (int fn = 0; fn < 4; ++fn) {
    int r = wc * 64 + fn * 16 + l16;
#pragma unroll
    for (int kk = 0; kk < 2; ++kk) boff[fn][kk] = 8192 + r * 128 + ((kk * 64 + lg * 16) ^ xm);
  }

  f32x4 z4 = {0.f, 0.f, 0.f, 0.f};
  f32x4 acc[2][4];
#pragma unroll
  for (int a = 0; a < 2; ++a)
#pragma unroll
    for (int b = 0; b < 4; ++b) acc[a][b] = z4;

  for (int kt = 0; kt < nk; ++kt) {
    __syncthreads();
#pragma unroll
    for (int j = 0; j < 2; ++j) *(f32x4*)(smem + dA[j]) = ra[j];
#pragma unroll
    for (int j = 0; j < 4; ++j) *(f32x4*)(smem + dB[j]) = rb[j];
    if (kt + 1 < nk) {  // prefetch next K-chunk into regs (hides L2 latency under compute)
#pragma unroll
      for (int j = 0; j < 2; ++j) { sA[j] += 128; ra[j] = *(const f32x4*)sA[j]; }
#pragma unroll
      for (int j = 0; j < 4; ++j) { sB[j] += 128; rb[j] = *(const f32x4*)sB[j]; }
    }
    __syncthreads();
#pragma unroll
    for (int kk = 0; kk < 2; ++kk) {
      bf16x8 av[2], bv[4];
#pragma unroll
      for (int fm = 0; fm < 2; ++fm) av[fm] = *(const bf16x8*)(smem + aoff[fm][kk]);
#pragma unroll
      for (int fn = 0; fn < 4; ++fn) bv[fn] = *(const bf16x8*)(smem + boff[fn][kk]);
#pragma unroll
      for (int fm = 0; fm < 2; ++fm)
#pragma unroll
        for (int fn = 0; fn < 4; ++fn)
          acc[fm][fn] = __builtin_amdgcn_mfma_f32_16x16x32_bf16(av[fm], bv[fn], acc[fm][fn], 0, 0, 0);
    }
  }

  // ---- epilogue: recombine gates in LDS, apply LSTM cell
  __syncthreads();
  float* gsm = (float*)smem;  // [64][128]
#pragma unroll
  for (int fm = 0; fm < 2; ++fm)
#pragma unroll
    for (int fn = 0; fn < 4; ++fn) {
      int col = wc * 64 + fn * 16 + l16;
#pragma unroll
      for (int j = 0; j < 4; ++j) {
        int row = wr * 32 + fm * 16 + lg * 4 + j;  // C/D: col=lane&15, row=(lane>>4)*4+reg
        gsm[row * 128 + col] = acc[fm][fn][j];
      }
    }
  __syncthreads();
#pragma unroll
  for (int i = 0; i < 8; ++i) {
    int p = tid + i * 256;            // 64 rows x 32 units
    int unit = p & 31, row = p >> 5;
    f32x4 g = *(const f32x4*)(gsm + row * 128 + unit * 4);
    f32x4 bb = *(const f32x4*)(bias + n0 + unit * 4);
    float ig = sigf(g.x + bb.x);
    float fg = sigf(g.y + bb.y);
    float gg = tanhf(g.z + bb.z);
    float og = sigf(g.w + bb.w);
    int grow = m0 + row, gu = (n0 >> 2) + unit;
    float cold = c_state[grow * RNN + gu];
    float cn = fg * cold + ig * gg;
    c_state[grow * RNN + gu] = cn;
    h_out[(size_t)grow * h_ld + gu] = __float2bfloat16(og * tanhf(cn));
  }
}

// ---------------------------------------------------------------------------
// K3: att = sigmoid(h2 @ WoT^T) fused with x=idea*att, heads -> out[b,t,0:2],
// plus the state copies for the next step (nt==0 blocks only):
//   x_bf[:,2048:2560] <- h_cat[:,0:512] (h1)   ;   h_cat[:,512:1024] <- h2b
// BM=128, BN=128, BK=64; 4 waves 2x2, wave tile 64x64.
// ---------------------------------------------------------------------------
__global__ void __launch_bounds__(256)
att_head(const char* __restrict__ Ab, const char* __restrict__ Bb,
         const float* __restrict__ bo,
         const __hip_bfloat16* __restrict__ idea_bf,
         __hip_bfloat16* __restrict__ x_bf,
         __hip_bfloat16* __restrict__ h_cat,
         const __hip_bfloat16* __restrict__ h2b,
         float* __restrict__ out, int t) {
  __shared__ char smem[32768]; // A[128][64] @0, B[128][64] @16384 (both swz)
  const int tid = threadIdx.x;
  const int m0 = blockIdx.x * 128;
  const int n0 = blockIdx.y * 128;
  const int kb = K3K * 2;

  if (blockIdx.y == 0) {  // state copies: safe (no att_head block reads these regions)
#pragma unroll
    for (int i = 0; i < 32; ++i) {
      int o = tid * 16 + i * 4096;  // 128 rows x 1024B
      int row = m0 + (o >> 10), cb = o & 1023;
      *(f32x4*)((char*)x_bf + (size_t)row * (K1K * 2) + CODE * 2 + cb) =
          *(const f32x4*)((const char*)h_cat + (size_t)row * (K2K * 2) + cb);
      *(f32x4*)((char*)h_cat + (size_t)row * (K2K * 2) + RNN * 2 + cb) =
          *(const f32x4*)((const char*)h2b + (size_t)row * (RNN * 2) + cb);
    }
  }

  const char* sA[4]; int dA[4];
  const char* sB[4]; int dB[4];
#pragma unroll
  for (int j = 0; j < 4; ++j) {
    int o = tid * 16 + j * 4096;
    int r = o >> 7, cb = o & 127;
    sA[j] = Ab + (size_t)(m0 + r) * kb + cb;
    dA[j] = swz(r, cb);
    sB[j] = Bb + (size_t)(n0 + r) * kb + cb;
    dB[j] = 16384 + swz(r, cb);
  }
  f32x4 ra[4], rb[4];
#pragma unroll
  for (int j = 0; j < 4; ++j) { ra[j] = *(const f32x4*)sA[j]; rb[j] = *(const f32x4*)sB[j]; }

  const int lane = tid & 63, l16 = lane & 15, lg = lane >> 4;
  const int wv = tid >> 6, wr = wv & 1, wc = wv >> 1;
  const int xm = (l16 & 7) << 4;

  int aoff[4][2], boff[4][2];
#pragma unroll
  for (int f = 0; f < 4; ++f) {
    int ra_ = wr * 64 + f * 16 + l16;
    int rb_ = wc * 64 + f * 16 + l16;
#pragma unroll
    for (int kk = 0; kk < 2; ++kk) {
      aoff[f][kk] = ra_ * 128 + ((kk * 64 + lg * 16) ^ xm);
      boff[f][kk] = 16384 + rb_ * 128 + ((kk * 64 + lg * 16) ^ xm);
    }
  }

  f32x4 z4 = {0.f, 0.f, 0.f, 0.f};
  f32x4 acc[4][4];
#pragma unroll
  for (int a = 0; a < 4; ++a)
#pragma unroll
    for (int b = 0; b < 4; ++b) acc[a][b] = z4;

  const int nk = K3K / 64;  // 8
  for (int kt = 0; kt < nk; ++kt) {
    __syncthreads();
#pragma unroll
    for (int j = 0; j < 4; ++j) { *(f32x4*)(smem + dA[j]) = ra[j]; *(f32x4*)(smem + dB[j]) = rb[j]; }
    if (kt + 1 < nk) {
#pragma unroll
      for (int j = 0; j < 4; ++j) {
        sA[j] += 128; ra[j] = *(const f32x4*)sA[j];
        sB[j] += 128; rb[j] = *(const f32x4*)sB[j];
      }
    }
    __syncthreads();
#pragma unroll
    for (int kk = 0; kk < 2; ++kk) {
      bf16x8 av[4], bv[4];
#pragma unroll
      for (int f = 0; f < 4; ++f) { av[f] = *(const bf16x8*)(smem + aoff[f][kk]); bv[f] = *(const bf16x8*)(smem + boff[f][kk]); }
#pragma unroll
      for (int fm = 0; fm < 4; ++fm)
#pragma unroll
        for (int fn = 0; fn < 4; ++fn)
          acc[fm][fn] = __builtin_amdgcn_mfma_f32_16x16x32_bf16(av[fm], bv[fn], acc[fm][fn], 0, 0, 0);
    }
  }

  // per-lane epilogue
#pragma unroll
  for (int fn = 0; fn < 4; ++fn) {
    int col = n0 + wc * 64 + fn * 16 + l16;
    float bia = bo[col];
    bool is_att = col < CODE;
#pragma unroll
    for (int fm = 0; fm < 4; ++fm)
#pragma unroll
      for (int j = 0; j < 4; ++j) {
        int row = m0 + wr * 64 + fm * 16 + lg * 4 + j;
        float v = acc[fm][fn][j] + bia;
        if (is_att) {
          float a = sigf(v);
          float id = __bfloat162float(idea_bf[(size_t)row * CODE + col]);
          x_bf[(size_t)row * K1K + col] = __float2bfloat16(id * a);
        } else if (col == CODE) {
          out[row * (TSTEPS * 2) + t * 2] = tanhf(v);
        } else if (col == CODE + 1) {
          out[row * (TSTEPS * 2) + t * 2 + 1] = sigf(v);
        }
      }
  }
}

// ---------------------------------------------------------------------------
extern "C" void kernel_launch(void* const* d_in, const int* in_sizes, int n_in,
                              void* d_out, int out_size, void* d_ws, size_t ws_size,
                              hipStream_t stream) {
  const float* latent = (const float*)d_in[0];
  const float* w_unp  = (const float*)d_in[2];
  const float* b_unp  = (const float*)d_in[3];
  const float* w_ih1  = (const float*)d_in[4];
  const float* w_hh1  = (const float*)d_in[5];
  const float* b_ih1  = (const float*)d_in[6];
  const float* b_hh1  = (const float*)d_in[7];
  const float* w_ih2  = (const float*)d_in[8];
  const float* w_hh2  = (const float*)d_in[9];
  const float* b_ih2  = (const float*)d_in[10];
  const float* b_hh2  = (const float*)d_in[11];
  const float* w_att  = (const float*)d_in[12];
  const float* b_att  = (const float*)d_in[13];
  const float* w_wid  = (const float*)d_in[14];
  const float* b_wid  = (const float*)d_in[15];
  const float* w_ang  = (const float*)d_in[16];
  const float* b_ang  = (const float*)d_in[17];
  float* out = (float*)d_out;

  char* ws = (char*)d_ws;
  __hip_bfloat16* W1T  = (__hip_bfloat16*)(ws + 0);          // 2048 x 2560 bf16
  __hip_bfloat16* W2T  = (__hip_bfloat16*)(ws + 10485760);   // 2048 x 1024
  __hip_bfloat16* WoT  = (__hip_bfloat16*)(ws + 14680064);   // 2176 x 512
  float* b1p           = (float*)(ws + 16908288);            // 2048
  float* b2p           = (float*)(ws + 16916480);            // 2048
  float* bo            = (float*)(ws + 16924672);            // 2176
  __hip_bfloat16* idea = (__hip_bfloat16*)(ws + 16933376);   // 1024 x 2048
  __hip_bfloat16* x_bf = (__hip_bfloat16*)(ws + 21127680);   // 1024 x 2560  [idea*att | h1]
  __hip_bfloat16* hcat = (__hip_bfloat16*)(ws + 26370560);   // 1024 x 1024  [h1 | h2]
  float* c1            = (float*)(ws + 28467712);            // 1024 x 512
  float* c2            = (float*)(ws + 30564864);            // 1024 x 512
  __hip_bfloat16* h2b  = (__hip_bfloat16*)(ws + 32662016);   // 1024 x 512

  conv_w1<<<2048, 256, 0, stream>>>(w_ih1, w_hh1, W1T);
  conv_w2<<<2048, 256, 0, stream>>>(w_ih2, w_hh2, W2T);
  conv_wo<<<2176, 256, 0, stream>>>(w_att, w_ang, w_wid, WoT);
  conv_b<<<9, 256, 0, stream>>>(b_ih1, b_hh1, b_ih2, b_hh2, b_att, b_ang, b_wid, b1p, b2p, bo);
  init_zero<<<1024, 256, 0, stream>>>(ws + 26370560, (char*)x_bf);
  idea_kernel<<<8192, 256, 0, stream>>>(latent, w_unp, b_unp, idea, x_bf);

  for (int t = 0; t < TSTEPS; ++t) {
    // gates1 = [idea*att, h1] @ W1 ; LSTM cell 1 -> c1, h1 (into hcat[:,0:512])
    lstm_gemm<<<dim3(16, 16), 256, 0, stream>>>((const char*)x_bf, (const char*)W1T,
                                                K1K, K1K / 64, b1p, c1, hcat, 1024);
    // gates2 = [h1, h2] @ W2 ; LSTM cell 2 -> c2, h2 (into h2b)
    lstm_gemm<<<dim3(16, 16), 256, 0, stream>>>((const char*)hcat, (const char*)W2T,
                                                K2K, K2K / 64, b2p, c2, h2b, 512);
    // att/heads: x = idea*sigmoid(h2@Watt), out[:,t,:] = [tanh, sigmoid]; copies for next step
    att_head<<<dim3(8, 17), 256, 0, stream>>>((const char*)h2b, (const char*)WoT,
                                              bo, idea, x_bf, hcat, h2b, out, t);
  }
}

// Round 2
// 7412.180 us; speedup vs baseline: 1.1066x; 1.1066x over previous
//
#include <hip/hip_runtime.h>
#include <hip/hip_bf16.h>
#include <cmath>

typedef __attribute__((ext_vector_type(8))) short bf16x8;
typedef __attribute__((ext_vector_type(4))) float f32x4;
typedef unsigned int u32;

#define DEVI __device__ __forceinline__

DEVI float sigf(float x) { return 1.0f / (1.0f + __expf(-x)); }

// async global->LDS, 16B per lane. LDS dest must be wave-uniform base (HW adds lane*16).
typedef const __attribute__((address_space(1))) u32* gas_t;
typedef __attribute__((address_space(3))) u32* las_t;
DEVI void g2l16(const void* g, void* l) {
  __builtin_amdgcn_global_load_lds((gas_t)g, (las_t)l, 16, 0, 0);
}

// ---- problem constants
#define BATCH 1024
#define CODE  2048
#define RNN   512
#define NG    2048      // 4*RNN
#define TSTEPS 128
#define K1K   2560      // CODE + RNN
#define K2K   1024      // RNN + RNN
#define K3K   512
#define NO    2176      // att cols padded: 2048 att + ang + wid + 126 pad (17 tiles of 128)

// ---------------------------------------------------------------------------
// prologue kernels (run every launch; d_ws is re-poisoned before each launch)
// ---------------------------------------------------------------------------

__global__ void conv_w1(const float* __restrict__ w_ih1, const float* __restrict__ w_hh1,
                        __hip_bfloat16* __restrict__ W1T) {
  int np = blockIdx.x;                       // 0..2047, gate-interleaved: np = 4u+g
  int co = (np & 3) * RNN + (np >> 2);       // original gate column
  for (int k = threadIdx.x; k < K1K; k += 256) {
    float v = (k < CODE) ? w_ih1[(size_t)k * NG + co]
                         : w_hh1[(size_t)(k - CODE) * NG + co];
    W1T[(size_t)np * K1K + k] = __float2bfloat16(v);
  }
}

__global__ void conv_w2(const float* __restrict__ w_ih2, const float* __restrict__ w_hh2,
                        __hip_bfloat16* __restrict__ W2T) {
  int np = blockIdx.x;
  int co = (np & 3) * RNN + (np >> 2);
  for (int k = threadIdx.x; k < K2K; k += 256) {
    float v = (k < RNN) ? w_ih2[(size_t)k * NG + co]
                        : w_hh2[(size_t)(k - RNN) * NG + co];
    W2T[(size_t)np * K2K + k] = __float2bfloat16(v);
  }
}

__global__ void conv_wo(const float* __restrict__ w_att, const float* __restrict__ w_ang,
                        const float* __restrict__ w_wid, __hip_bfloat16* __restrict__ WoT) {
  int n = blockIdx.x;  // 0..2175
  for (int k = threadIdx.x; k < K3K; k += 256) {
    float v = 0.f;
    if (n < CODE) v = w_att[(size_t)k * CODE + n];
    else if (n == CODE) v = w_ang[k];
    else if (n == CODE + 1) v = w_wid[k];
    WoT[(size_t)n * K3K + k] = __float2bfloat16(v);
  }
}

__global__ void conv_b(const float* b_ih1, const float* b_hh1,
                       const float* b_ih2, const float* b_hh2,
                       const float* b_att, const float* b_ang, const float* b_wid,
                       float* b1p, float* b2p, float* bo) {
  int i = blockIdx.x * 256 + threadIdx.x;
  if (i < NG) {
    int co = (i & 3) * RNN + (i >> 2);
    b1p[i] = b_ih1[co] + b_hh1[co];
    b2p[i] = b_ih2[co] + b_hh2[co];
  }
  if (i < NO) {
    float v = 0.f;
    if (i < CODE) v = b_att[i];
    else if (i == CODE) v = b_ang[0];
    else if (i == CODE + 1) v = b_wid[0];
    bo[i] = v;
  }
}

// zero h_cat(2MB)+c1(2MB)+c2(2MB) contiguous + the h1 strip of x_bf
__global__ void init_zero(char* __restrict__ zb, char* __restrict__ xb) {
  int idx = blockIdx.x * 256 + threadIdx.x;       // 262144 threads
  f32x4 z = {0.f, 0.f, 0.f, 0.f};
  for (int i = idx; i < 393216; i += 262144) *(f32x4*)(zb + (size_t)i * 16) = z;
  for (int i = idx; i < 65536; i += 262144) {
    int row = i >> 6, j = i & 63;
    *(f32x4*)(xb + (size_t)row * (K1K * 2) + CODE * 2 + (size_t)j * 16) = z;
  }
}

// idea = tanh(latent @ w_unpack + b); also x_bf[:,0:2048] = idea (att0 = 1)
__global__ void idea_kernel(const float* __restrict__ latent, const float* __restrict__ w,
                            const float* __restrict__ b,
                            __hip_bfloat16* __restrict__ idea_bf,
                            __hip_bfloat16* __restrict__ x_bf) {
  int idx = blockIdx.x * 256 + threadIdx.x;       // 2M = 1024*2048
  int bi = idx >> 11, j = idx & 2047;
  const float* lr = latent + bi * 128;
  float s = b[j];
#pragma unroll 8
  for (int k = 0; k < 128; ++k) s = fmaf(lr[k], w[(size_t)k * CODE + j], s);
  __hip_bfloat16 h = __float2bfloat16(tanhf(s));
  idea_bf[idx] = h;
  x_bf[(size_t)bi * K1K + j] = h;
}

// ---------------------------------------------------------------------------
// Fused GEMM + LSTM cell. C = A[1024,K] @ BT[2048,K]^T, gate-interleaved N.
// BM=64, BN=128, BK=64; 4 waves 2x2, wave tile 32x64.
// Staging: global_load_lds dwordx4, pre-swizzled SOURCE address + linear LDS
// dest (involution: LDS[r*128+q] holds global (r, q ^ ((r&7)<<4))), double-
// buffered. Reads use the matching XOR so ds_read_b128 is conflict-free.
// XCD swizzle: xcd=bid&7 owns n-tiles {2*xcd, 2*xcd+1} -> W slice 1.25MB in L2.
// ---------------------------------------------------------------------------
__global__ void __launch_bounds__(256)
lstm_gemm(const char* __restrict__ Ab, const char* __restrict__ Bb,
          int K, int nk, const float* __restrict__ bias,
          float* __restrict__ c_state, __hip_bfloat16* __restrict__ h_out, int h_ld) {
  __shared__ char smem[49152];  // 2 x (A 8KB + B 16KB); epilogue reuses 32KB as f32[64][128]
  const int tid = threadIdx.x;
  const int l = blockIdx.x;              // 256 blocks
  const int xcd = l & 7, bi = l >> 3;
  const int n0 = ((xcd << 1) | (bi & 1)) * 128;
  const int m0 = (bi >> 1) * 64;
  const int kb = K * 2;

  const int lane = tid & 63, wv = tid >> 6;
  const int rl = lane >> 3;              // row-in-8-group
  const int cswz = ((lane & 7) * 16) ^ (rl << 4);   // pre-swizzled source column

  // per-wave: 6 of the 24 1KB-chunks (A: 0..7 -> rows m0+.., B: 8..23 -> rows n0+..)
  const char* gp[6];
  int ldsc[6];
#pragma unroll
  for (int j = 0; j < 6; ++j) {
    int c = wv * 6 + j;
    int row = (c < 8) ? (m0 + c * 8 + rl) : (n0 + (c - 8) * 8 + rl);
    const char* base = (c < 8) ? Ab : Bb;
    gp[j] = base + (size_t)row * kb + cswz;
    ldsc[j] = c * 1024;
  }

  const int l16 = lane & 15, lg = lane >> 4;
  const int wr = wv & 1, wc = wv >> 1;
  const int xm = (l16 & 7) << 4;

  int aoff[2][2], boff[4][2];
#pragma unroll
  for (int fm = 0; fm < 2; ++fm) {
    int r = wr * 32 + fm * 16 + l16;
#pragma unroll
    for (int kk = 0; kk < 2; ++kk) aoff[fm][kk] = r * 128 + ((kk * 64 + lg * 16) ^ xm);
  }
#pragma unroll
  for (int fn = 0; fn < 4; ++fn) {
    int r = wc * 64 + fn * 16 + l16;
#pragma unroll
    for (int kk = 0; kk < 2; ++kk) boff[fn][kk] = 8192 + r * 128 + ((kk * 64 + lg * 16) ^ xm);
  }

  f32x4 z4 = {0.f, 0.f, 0.f, 0.f};
  f32x4 acc[2][4];
#pragma unroll
  for (int a = 0; a < 2; ++a)
#pragma unroll
    for (int b = 0; b < 4; ++b) acc[a][b] = z4;

  // prologue: stage K-chunk 0 into buffer 0
#pragma unroll
  for (int j = 0; j < 6; ++j) g2l16(gp[j], smem + ldsc[j]);

  int cur = 0;
  for (int kt = 0; kt < nk; ++kt) {
    __syncthreads();                      // drains vmcnt -> buf[cur] ready
    if (kt + 1 < nk) {                    // prefetch next K-chunk into the other buffer
      int nb = (cur ^ 1) * 24576;
      size_t ko = (size_t)(kt + 1) * 128;
#pragma unroll
      for (int j = 0; j < 6; ++j) g2l16(gp[j] + ko, smem + nb + ldsc[j]);
    }
    const char* sb = smem + cur * 24576;
#pragma unroll
    for (int kk = 0; kk < 2; ++kk) {
      bf16x8 av[2], bv[4];
#pragma unroll
      for (int fm = 0; fm < 2; ++fm) av[fm] = *(const bf16x8*)(sb + aoff[fm][kk]);
#pragma unroll
      for (int fn = 0; fn < 4; ++fn) bv[fn] = *(const bf16x8*)(sb + boff[fn][kk]);
#pragma unroll
      for (int fm = 0; fm < 2; ++fm)
#pragma unroll
        for (int fn = 0; fn < 4; ++fn)
          acc[fm][fn] = __builtin_amdgcn_mfma_f32_16x16x32_bf16(av[fm], bv[fn], acc[fm][fn], 0, 0, 0);
    }
    cur ^= 1;
  }

  // ---- epilogue: recombine gates in LDS, apply LSTM cell
  __syncthreads();
  float* gsm = (float*)smem;  // [64][128]
#pragma unroll
  for (int fm = 0; fm < 2; ++fm)
#pragma unroll
    for (int fn = 0; fn < 4; ++fn) {
      int col = wc * 64 + fn * 16 + l16;
#pragma unroll
      for (int j = 0; j < 4; ++j) {
        int row = wr * 32 + fm * 16 + lg * 4 + j;  // C/D: col=lane&15, row=(lane>>4)*4+reg
        gsm[row * 128 + col] = acc[fm][fn][j];
      }
    }
  __syncthreads();
#pragma unroll
  for (int i = 0; i < 8; ++i) {
    int p = tid + i * 256;            // 64 rows x 32 units
    int unit = p & 31, row = p >> 5;
    f32x4 g = *(const f32x4*)(gsm + row * 128 + unit * 4);
    f32x4 bb = *(const f32x4*)(bias + n0 + unit * 4);
    float ig = sigf(g.x + bb.x);
    float fg = sigf(g.y + bb.y);
    float gg = tanhf(g.z + bb.z);
    float og = sigf(g.w + bb.w);
    int grow = m0 + row, gu = (n0 >> 2) + unit;
    float cold = c_state[grow * RNN + gu];
    float cn = fg * cold + ig * gg;
    c_state[grow * RNN + gu] = cn;
    h_out[(size_t)grow * h_ld + gu] = __float2bfloat16(og * tanhf(cn));
  }
}

// ---------------------------------------------------------------------------
// K3: att = sigmoid(h2 @ WoT^T) fused with x=idea*att, heads -> out[b,t,:],
// plus state copies (blockIdx.y==0 blocks):
//   x_bf[:,2048:2560] <- h_cat[:,0:512] (h1) ;  h_cat[:,512:1024] <- h2b
// BM=64, BN=128, grid 16x17 = 272 blocks; same staging core as lstm_gemm.
// ---------------------------------------------------------------------------
__global__ void __launch_bounds__(256)
att_head(const char* __restrict__ Ab, const char* __restrict__ Bb,
         const float* __restrict__ bo,
         const __hip_bfloat16* __restrict__ idea_bf,
         __hip_bfloat16* __restrict__ x_bf,
         __hip_bfloat16* __restrict__ h_cat,
         const __hip_bfloat16* __restrict__ h2b,
         float* __restrict__ out, int t) {
  __shared__ char smem[49152];
  const int tid = threadIdx.x;
  const int m0 = blockIdx.x * 64;
  const int n0 = blockIdx.y * 128;
  const int kb = K3K * 2;

  if (blockIdx.y == 0) {  // state copies for next step (regions disjoint from GEMM reads)
#pragma unroll
    for (int i = 0; i < 16; ++i) {
      int o = tid * 16 + i * 4096;  // 64 rows x 1024B
      int row = m0 + (o >> 10), cb = o & 1023;
      *(f32x4*)((char*)x_bf + (size_t)row * (K1K * 2) + CODE * 2 + cb) =
          *(const f32x4*)((const char*)h_cat + (size_t)row * (K2K * 2) + cb);
      *(f32x4*)((char*)h_cat + (size_t)row * (K2K * 2) + RNN * 2 + cb) =
          *(const f32x4*)((const char*)h2b + (size_t)row * (RNN * 2) + cb);
    }
  }

  const int lane = tid & 63, wv = tid >> 6;
  const int rl = lane >> 3;
  const int cswz = ((lane & 7) * 16) ^ (rl << 4);

  const char* gp[6];
  int ldsc[6];
#pragma unroll
  for (int j = 0; j < 6; ++j) {
    int c = wv * 6 + j;
    int row = (c < 8) ? (m0 + c * 8 + rl) : (n0 + (c - 8) * 8 + rl);
    const char* base = (c < 8) ? Ab : Bb;
    gp[j] = base + (size_t)row * kb + cswz;
    ldsc[j] = c * 1024;
  }

  const int l16 = lane & 15, lg = lane >> 4;
  const int wr = wv & 1, wc = wv >> 1;
  const int xm = (l16 & 7) << 4;

  int aoff[2][2], boff[4][2];
#pragma unroll
  for (int fm = 0; fm < 2; ++fm) {
    int r = wr * 32 + fm * 16 + l16;
#pragma unroll
    for (int kk = 0; kk < 2; ++kk) aoff[fm][kk] = r * 128 + ((kk * 64 + lg * 16) ^ xm);
  }
#pragma unroll
  for (int fn = 0; fn < 4; ++fn) {
    int r = wc * 64 + fn * 16 + l16;
#pragma unroll
    for (int kk = 0; kk < 2; ++kk) boff[fn][kk] = 8192 + r * 128 + ((kk * 64 + lg * 16) ^ xm);
  }

  f32x4 z4 = {0.f, 0.f, 0.f, 0.f};
  f32x4 acc[2][4];
#pragma unroll
  for (int a = 0; a < 2; ++a)
#pragma unroll
    for (int b = 0; b < 4; ++b) acc[a][b] = z4;

#pragma unroll
  for (int j = 0; j < 6; ++j) g2l16(gp[j], smem + ldsc[j]);

  int cur = 0;
  const int nk = K3K / 64;  // 8
  for (int kt = 0; kt < nk; ++kt) {
    __syncthreads();
    if (kt + 1 < nk) {
      int nb = (cur ^ 1) * 24576;
      size_t ko = (size_t)(kt + 1) * 128;
#pragma unroll
      for (int j = 0; j < 6; ++j) g2l16(gp[j] + ko, smem + nb + ldsc[j]);
    }
    const char* sb = smem + cur * 24576;
#pragma unroll
    for (int kk = 0; kk < 2; ++kk) {
      bf16x8 av[2], bv[4];
#pragma unroll
      for (int fm = 0; fm < 2; ++fm) av[fm] = *(const bf16x8*)(sb + aoff[fm][kk]);
#pragma unroll
      for (int fn = 0; fn < 4; ++fn) bv[fn] = *(const bf16x8*)(sb + boff[fn][kk]);
#pragma unroll
      for (int fm = 0; fm < 2; ++fm)
#pragma unroll
        for (int fn = 0; fn < 4; ++fn)
          acc[fm][fn] = __builtin_amdgcn_mfma_f32_16x16x32_bf16(av[fm], bv[fn], acc[fm][fn], 0, 0, 0);
    }
    cur ^= 1;
  }

  // per-lane epilogue
#pragma unroll
  for (int fn = 0; fn < 4; ++fn) {
    int col = n0 + wc * 64 + fn * 16 + l16;
    float bia = bo[col];
    bool is_att = col < CODE;
#pragma unroll
    for (int fm = 0; fm < 2; ++fm)
#pragma unroll
      for (int j = 0; j < 4; ++j) {
        int row = m0 + wr * 32 + fm * 16 + lg * 4 + j;
        float v = acc[fm][fn][j] + bia;
        if (is_att) {
          float a = sigf(v);
          float id = __bfloat162float(idea_bf[(size_t)row * CODE + col]);
          x_bf[(size_t)row * K1K + col] = __float2bfloat16(id * a);
        } else if (col == CODE) {
          out[row * (TSTEPS * 2) + t * 2] = tanhf(v);
        } else if (col == CODE + 1) {
          out[row * (TSTEPS * 2) + t * 2 + 1] = sigf(v);
        }
      }
  }
}

// ---------------------------------------------------------------------------
extern "C" void kernel_launch(void* const* d_in, const int* in_sizes, int n_in,
                              void* d_out, int out_size, void* d_ws, size_t ws_size,
                              hipStream_t stream) {
  const float* latent = (const float*)d_in[0];
  const float* w_unp  = (const float*)d_in[2];
  const float* b_unp  = (const float*)d_in[3];
  const float* w_ih1  = (const float*)d_in[4];
  const float* w_hh1  = (const float*)d_in[5];
  const float* b_ih1  = (const float*)d_in[6];
  const float* b_hh1  = (const float*)d_in[7];
  const float* w_ih2  = (const float*)d_in[8];
  const float* w_hh2  = (const float*)d_in[9];
  const float* b_ih2  = (const float*)d_in[10];
  const float* b_hh2  = (const float*)d_in[11];
  const float* w_att  = (const float*)d_in[12];
  const float* b_att  = (const float*)d_in[13];
  const float* w_wid  = (const float*)d_in[14];
  const float* b_wid  = (const float*)d_in[15];
  const float* w_ang  = (const float*)d_in[16];
  const float* b_ang  = (const float*)d_in[17];
  float* out = (float*)d_out;

  char* ws = (char*)d_ws;
  __hip_bfloat16* W1T  = (__hip_bfloat16*)(ws + 0);          // 2048 x 2560 bf16
  __hip_bfloat16* W2T  = (__hip_bfloat16*)(ws + 10485760);   // 2048 x 1024
  __hip_bfloat16* WoT  = (__hip_bfloat16*)(ws + 14680064);   // 2176 x 512
  float* b1p           = (float*)(ws + 16908288);            // 2048
  float* b2p           = (float*)(ws + 16916480);            // 2048
  float* bo            = (float*)(ws + 16924672);            // 2176
  __hip_bfloat16* idea = (__hip_bfloat16*)(ws + 16933376);   // 1024 x 2048
  __hip_bfloat16* x_bf = (__hip_bfloat16*)(ws + 21127680);   // 1024 x 2560  [idea*att | h1]
  __hip_bfloat16* hcat = (__hip_bfloat16*)(ws + 26370560);   // 1024 x 1024  [h1 | h2]
  float* c1            = (float*)(ws + 28467712);            // 1024 x 512
  float* c2            = (float*)(ws + 30564864);            // 1024 x 512
  __hip_bfloat16* h2b  = (__hip_bfloat16*)(ws + 32662016);   // 1024 x 512

  conv_w1<<<2048, 256, 0, stream>>>(w_ih1, w_hh1, W1T);
  conv_w2<<<2048, 256, 0, stream>>>(w_ih2, w_hh2, W2T);
  conv_wo<<<2176, 256, 0, stream>>>(w_att, w_ang, w_wid, WoT);
  conv_b<<<9, 256, 0, stream>>>(b_ih1, b_hh1, b_ih2, b_hh2, b_att, b_ang, b_wid, b1p, b2p, bo);
  init_zero<<<1024, 256, 0, stream>>>(ws + 26370560, (char*)x_bf);
  idea_kernel<<<8192, 256, 0, stream>>>(latent, w_unp, b_unp, idea, x_bf);

  for (int t = 0; t < TSTEPS; ++t) {
    lstm_gemm<<<256, 256, 0, stream>>>((const char*)x_bf, (const char*)W1T,
                                       K1K, K1K / 64, b1p, c1, hcat, 1024);
    lstm_gemm<<<256, 256, 0, stream>>>((const char*)hcat, (const char*)W2T,
                                       K2K, K2K / 64, b2p, c2, h2b, 512);
    att_head<<<dim3(16, 17), 256, 0, stream>>>((const char*)h2b, (const char*)WoT,
                                               bo, idea, x_bf, hcat, h2b, out, t);
  }
}

// Round 3
// 6543.291 us; speedup vs baseline: 1.2536x; 1.1328x over previous
//
#include <hip/hip_runtime.h>
#include <hip/hip_bf16.h>
#include <cmath>

typedef __attribute__((ext_vector_type(8))) short bf16x8;
typedef __attribute__((ext_vector_type(4))) float f32x4;
typedef unsigned int u32;

#define DEVI __device__ __forceinline__

DEVI float sigf(float x) { return 1.0f / (1.0f + __expf(-x)); }

// async global->LDS, 16B per lane. LDS dest must be wave-uniform base (HW adds lane*16).
typedef const __attribute__((address_space(1))) u32* gas_t;
typedef __attribute__((address_space(3))) u32* las_t;
DEVI void g2l16(const void* g, void* l) {
  __builtin_amdgcn_global_load_lds((gas_t)g, (las_t)l, 16, 0, 0);
}

// ---- problem constants
#define BATCH 1024
#define CODE  2048
#define RNN   512
#define NG    2048      // 4*RNN
#define TSTEPS 128
#define K1K   2560      // CODE + RNN
#define K2K   1024      // RNN + RNN
#define K3K   512
#define NO    2176      // att cols padded: 2048 att + ang + wid + 126 pad (17 tiles of 128)

#define BUFSZ 24576     // one K-tile stage: A 8KB + B 16KB

// ---------------------------------------------------------------------------
// prologue kernels (run every launch; d_ws is re-poisoned before each launch)
// ---------------------------------------------------------------------------

__global__ void conv_w1(const float* __restrict__ w_ih1, const float* __restrict__ w_hh1,
                        __hip_bfloat16* __restrict__ W1T) {
  int np = blockIdx.x;                       // 0..2047, gate-interleaved: np = 4u+g
  int co = (np & 3) * RNN + (np >> 2);       // original gate column
  for (int k = threadIdx.x; k < K1K; k += 256) {
    float v = (k < CODE) ? w_ih1[(size_t)k * NG + co]
                         : w_hh1[(size_t)(k - CODE) * NG + co];
    W1T[(size_t)np * K1K + k] = __float2bfloat16(v);
  }
}

__global__ void conv_w2(const float* __restrict__ w_ih2, const float* __restrict__ w_hh2,
                        __hip_bfloat16* __restrict__ W2T) {
  int np = blockIdx.x;
  int co = (np & 3) * RNN + (np >> 2);
  for (int k = threadIdx.x; k < K2K; k += 256) {
    float v = (k < RNN) ? w_ih2[(size_t)k * NG + co]
                        : w_hh2[(size_t)(k - RNN) * NG + co];
    W2T[(size_t)np * K2K + k] = __float2bfloat16(v);
  }
}

__global__ void conv_wo(const float* __restrict__ w_att, const float* __restrict__ w_ang,
                        const float* __restrict__ w_wid, __hip_bfloat16* __restrict__ WoT) {
  int n = blockIdx.x;  // 0..2175
  for (int k = threadIdx.x; k < K3K; k += 256) {
    float v = 0.f;
    if (n < CODE) v = w_att[(size_t)k * CODE + n];
    else if (n == CODE) v = w_ang[k];
    else if (n == CODE + 1) v = w_wid[k];
    WoT[(size_t)n * K3K + k] = __float2bfloat16(v);
  }
}

__global__ void conv_b(const float* b_ih1, const float* b_hh1,
                       const float* b_ih2, const float* b_hh2,
                       const float* b_att, const float* b_ang, const float* b_wid,
                       float* b1p, float* b2p, float* bo) {
  int i = blockIdx.x * 256 + threadIdx.x;
  if (i < NG) {
    int co = (i & 3) * RNN + (i >> 2);
    b1p[i] = b_ih1[co] + b_hh1[co];
    b2p[i] = b_ih2[co] + b_hh2[co];
  }
  if (i < NO) {
    float v = 0.f;
    if (i < CODE) v = b_att[i];
    else if (i == CODE) v = b_ang[0];
    else if (i == CODE + 1) v = b_wid[0];
    bo[i] = v;
  }
}

// zero h_cat(2MB)+c1(2MB)+c2(2MB) contiguous + the h1 strip of x_bf
__global__ void init_zero(char* __restrict__ zb, char* __restrict__ xb) {
  int idx = blockIdx.x * 256 + threadIdx.x;       // 262144 threads
  f32x4 z = {0.f, 0.f, 0.f, 0.f};
  for (int i = idx; i < 393216; i += 262144) *(f32x4*)(zb + (size_t)i * 16) = z;
  for (int i = idx; i < 65536; i += 262144) {
    int row = i >> 6, j = i & 63;
    *(f32x4*)(xb + (size_t)row * (K1K * 2) + CODE * 2 + (size_t)j * 16) = z;
  }
}

// idea = tanh(latent @ w_unpack + b); also x_bf[:,0:2048] = idea (att0 = 1)
__global__ void idea_kernel(const float* __restrict__ latent, const float* __restrict__ w,
                            const float* __restrict__ b,
                            __hip_bfloat16* __restrict__ idea_bf,
                            __hip_bfloat16* __restrict__ x_bf) {
  int idx = blockIdx.x * 256 + threadIdx.x;       // 2M = 1024*2048
  int bi = idx >> 11, j = idx & 2047;
  const float* lr = latent + bi * 128;
  float s = b[j];
#pragma unroll 8
  for (int k = 0; k < 128; ++k) s = fmaf(lr[k], w[(size_t)k * CODE + j], s);
  __hip_bfloat16 h = __float2bfloat16(tanhf(s));
  idea_bf[idx] = h;
  x_bf[(size_t)bi * K1K + j] = h;
}

// ---- shared GEMM inner-loop fragments -------------------------------------

#define STAGE(KO, DST)                                                        \
  _Pragma("unroll") for (int j = 0; j < 6; ++j)                               \
      g2l16(gp[j] + (KO), (DST) + ldsc[j]);

#define COMPUTE(SB)                                                           \
  _Pragma("unroll") for (int kk = 0; kk < 2; ++kk) {                          \
    bf16x8 av[2], bv[4];                                                      \
    _Pragma("unroll") for (int fm = 0; fm < 2; ++fm)                          \
        av[fm] = *(const bf16x8*)((SB) + aoff[fm][kk]);                       \
    _Pragma("unroll") for (int fn = 0; fn < 4; ++fn)                          \
        bv[fn] = *(const bf16x8*)((SB) + boff[fn][kk]);                       \
    _Pragma("unroll") for (int fm = 0; fm < 2; ++fm)                          \
      _Pragma("unroll") for (int fn = 0; fn < 4; ++fn)                        \
        acc[fm][fn] = __builtin_amdgcn_mfma_f32_16x16x32_bf16(                \
            av[fm], bv[fn], acc[fm][fn], 0, 0, 0);                            \
  }

#define WAITB(N)                                                              \
  asm volatile("s_waitcnt vmcnt(" #N ")" ::: "memory");                       \
  __builtin_amdgcn_s_barrier();                                               \
  asm volatile("" ::: "memory");

// ---------------------------------------------------------------------------
// Fused GEMM + LSTM cell. C = A[1024,K] @ BT[2048,K]^T, gate-interleaved N.
// BM=64, BN=128, BK=64; 4 waves 2x2, wave tile 32x64.
// Staging: global_load_lds dwordx4, pre-swizzled SOURCE + linear LDS dest
// (involution: LDS[r*128+q] holds global (r, q ^ ((r&7)<<4))).
// Pipeline: 3 LDS buffers, prefetch depth 2, counted s_waitcnt vmcnt(6)
// (never 0 in steady state) + raw s_barrier -- loads stay in flight across
// barriers (T3+T4).
// XCD swizzle: xcd=bid&7 owns n-tiles {2*xcd, 2*xcd+1} -> W slice L2-resident.
// ---------------------------------------------------------------------------
__global__ void __launch_bounds__(256)
lstm_gemm(const char* __restrict__ Ab, const char* __restrict__ Bb,
          int K, int nk, const float* __restrict__ bias,
          float* __restrict__ c_state, __hip_bfloat16* __restrict__ h_out, int h_ld) {
  __shared__ char smem[3 * BUFSZ];  // 72KB; epilogue reuses 32KB as f32[64][128]
  const int tid = threadIdx.x;
  const int l = blockIdx.x;              // 256 blocks
  const int xcd = l & 7, bi = l >> 3;
  const int n0 = ((xcd << 1) | (bi & 1)) * 128;
  const int m0 = (bi >> 1) * 64;
  const int kb = K * 2;

  const int lane = tid & 63, wv = tid >> 6;
  const int rl = lane >> 3;              // row-in-8-group
  const int cswz = ((lane & 7) * 16) ^ (rl << 4);   // pre-swizzled source column

  // per-wave: 6 of the 24 1KB-chunks (A: 0..7 -> rows m0+.., B: 8..23 -> rows n0+..)
  const char* gp[6];
  int ldsc[6];
#pragma unroll
  for (int j = 0; j < 6; ++j) {
    int c = wv * 6 + j;
    int row = (c < 8) ? (m0 + c * 8 + rl) : (n0 + (c - 8) * 8 + rl);
    const char* base = (c < 8) ? Ab : Bb;
    gp[j] = base + (size_t)row * kb + cswz;
    ldsc[j] = c * 1024;
  }

  const int l16 = lane & 15, lg = lane >> 4;
  const int wr = wv & 1, wc = wv >> 1;
  const int xm = (l16 & 7) << 4;

  int aoff[2][2], boff[4][2];
#pragma unroll
  for (int fm = 0; fm < 2; ++fm) {
    int r = wr * 32 + fm * 16 + l16;
#pragma unroll
    for (int kk = 0; kk < 2; ++kk) aoff[fm][kk] = r * 128 + ((kk * 64 + lg * 16) ^ xm);
  }
#pragma unroll
  for (int fn = 0; fn < 4; ++fn) {
    int r = wc * 64 + fn * 16 + l16;
#pragma unroll
    for (int kk = 0; kk < 2; ++kk) boff[fn][kk] = 8192 + r * 128 + ((kk * 64 + lg * 16) ^ xm);
  }

  f32x4 z4 = {0.f, 0.f, 0.f, 0.f};
  f32x4 acc[2][4];
#pragma unroll
  for (int a = 0; a < 2; ++a)
#pragma unroll
    for (int b = 0; b < 4; ++b) acc[a][b] = z4;

  // prologue: stage K-tiles 0 and 1
  STAGE(0, smem);
  STAGE(128, smem + BUFSZ);

  for (int kt = 0; kt < nk - 1; ++kt) {
    WAITB(6);                             // own tile-kt loads done; barrier publishes all
    if (kt + 2 < nk) {
      char* nb = smem + ((kt + 2) % 3) * BUFSZ;
      STAGE((size_t)(kt + 2) * 128, nb);
    }
    const char* sb = smem + (kt % 3) * BUFSZ;
    COMPUTE(sb);
  }
  WAITB(0);
  COMPUTE(smem + ((nk - 1) % 3) * BUFSZ);

  // ---- epilogue: recombine gates in LDS, apply LSTM cell
  __syncthreads();
  float* gsm = (float*)smem;  // [64][128]
#pragma unroll
  for (int fm = 0; fm < 2; ++fm)
#pragma unroll
    for (int fn = 0; fn < 4; ++fn) {
      int col = wc * 64 + fn * 16 + l16;
#pragma unroll
      for (int j = 0; j < 4; ++j) {
        int row = wr * 32 + fm * 16 + lg * 4 + j;  // C/D: col=lane&15, row=(lane>>4)*4+reg
        gsm[row * 128 + col] = acc[fm][fn][j];
      }
    }
  __syncthreads();
#pragma unroll
  for (int i = 0; i < 8; ++i) {
    int p = tid + i * 256;            // 64 rows x 32 units
    int unit = p & 31, row = p >> 5;
    f32x4 g = *(const f32x4*)(gsm + row * 128 + unit * 4);
    f32x4 bb = *(const f32x4*)(bias + n0 + unit * 4);
    float ig = sigf(g.x + bb.x);
    float fg = sigf(g.y + bb.y);
    float gg = tanhf(g.z + bb.z);
    float og = sigf(g.w + bb.w);
    int grow = m0 + row, gu = (n0 >> 2) + unit;
    float cold = c_state[grow * RNN + gu];
    float cn = fg * cold + ig * gg;
    c_state[grow * RNN + gu] = cn;
    h_out[(size_t)grow * h_ld + gu] = __float2bfloat16(og * tanhf(cn));
  }
}

// ---------------------------------------------------------------------------
// K3: att = sigmoid(h2 @ WoT^T) fused with x=idea*att, heads -> out[b,t,:],
// plus state copies (blockIdx.y==0 blocks):
//   x_bf[:,2048:2560] <- h_cat[:,0:512] (h1) ;  h_cat[:,512:1024] <- h2b
// BM=64, BN=128, grid 16x17; same pipelined core as lstm_gemm.
// ---------------------------------------------------------------------------
__global__ void __launch_bounds__(256)
att_head(const char* __restrict__ Ab, const char* __restrict__ Bb,
         const float* __restrict__ bo,
         const __hip_bfloat16* __restrict__ idea_bf,
         __hip_bfloat16* __restrict__ x_bf,
         __hip_bfloat16* __restrict__ h_cat,
         const __hip_bfloat16* __restrict__ h2b,
         float* __restrict__ out, int t) {
  __shared__ char smem[3 * BUFSZ];
  const int tid = threadIdx.x;
  const int m0 = blockIdx.x * 64;
  const int n0 = blockIdx.y * 128;
  const int kb = K3K * 2;

  if (blockIdx.y == 0) {  // state copies for next step (regions disjoint from GEMM reads)
#pragma unroll
    for (int i = 0; i < 16; ++i) {
      int o = tid * 16 + i * 4096;  // 64 rows x 1024B
      int row = m0 + (o >> 10), cb = o & 1023;
      *(f32x4*)((char*)x_bf + (size_t)row * (K1K * 2) + CODE * 2 + cb) =
          *(const f32x4*)((const char*)h_cat + (size_t)row * (K2K * 2) + cb);
      *(f32x4*)((char*)h_cat + (size_t)row * (K2K * 2) + RNN * 2 + cb) =
          *(const f32x4*)((const char*)h2b + (size_t)row * (RNN * 2) + cb);
    }
  }

  const int lane = tid & 63, wv = tid >> 6;
  const int rl = lane >> 3;
  const int cswz = ((lane & 7) * 16) ^ (rl << 4);

  const char* gp[6];
  int ldsc[6];
#pragma unroll
  for (int j = 0; j < 6; ++j) {
    int c = wv * 6 + j;
    int row = (c < 8) ? (m0 + c * 8 + rl) : (n0 + (c - 8) * 8 + rl);
    const char* base = (c < 8) ? Ab : Bb;
    gp[j] = base + (size_t)row * kb + cswz;
    ldsc[j] = c * 1024;
  }

  const int l16 = lane & 15, lg = lane >> 4;
  const int wr = wv & 1, wc = wv >> 1;
  const int xm = (l16 & 7) << 4;

  int aoff[2][2], boff[4][2];
#pragma unroll
  for (int fm = 0; fm < 2; ++fm) {
    int r = wr * 32 + fm * 16 + l16;
#pragma unroll
    for (int kk = 0; kk < 2; ++kk) aoff[fm][kk] = r * 128 + ((kk * 64 + lg * 16) ^ xm);
  }
#pragma unroll
  for (int fn = 0; fn < 4; ++fn) {
    int r = wc * 64 + fn * 16 + l16;
#pragma unroll
    for (int kk = 0; kk < 2; ++kk) boff[fn][kk] = 8192 + r * 128 + ((kk * 64 + lg * 16) ^ xm);
  }

  f32x4 z4 = {0.f, 0.f, 0.f, 0.f};
  f32x4 acc[2][4];
#pragma unroll
  for (int a = 0; a < 2; ++a)
#pragma unroll
    for (int b = 0; b < 4; ++b) acc[a][b] = z4;

  const int nk = K3K / 64;  // 8
  STAGE(0, smem);
  STAGE(128, smem + BUFSZ);

  for (int kt = 0; kt < nk - 1; ++kt) {
    WAITB(6);
    if (kt + 2 < nk) {
      char* nb = smem + ((kt + 2) % 3) * BUFSZ;
      STAGE((size_t)(kt + 2) * 128, nb);
    }
    const char* sb = smem + (kt % 3) * BUFSZ;
    COMPUTE(sb);
  }
  WAITB(0);
  COMPUTE(smem + ((nk - 1) % 3) * BUFSZ);

  // per-lane epilogue
#pragma unroll
  for (int fn = 0; fn < 4; ++fn) {
    int col = n0 + wc * 64 + fn * 16 + l16;
    float bia = bo[col];
    bool is_att = col < CODE;
#pragma unroll
    for (int fm = 0; fm < 2; ++fm)
#pragma unroll
      for (int j = 0; j < 4; ++j) {
        int row = m0 + wr * 32 + fm * 16 + lg * 4 + j;
        float v = acc[fm][fn][j] + bia;
        if (is_att) {
          float a = sigf(v);
          float id = __bfloat162float(idea_bf[(size_t)row * CODE + col]);
          x_bf[(size_t)row * K1K + col] = __float2bfloat16(id * a);
        } else if (col == CODE) {
          out[row * (TSTEPS * 2) + t * 2] = tanhf(v);
        } else if (col == CODE + 1) {
          out[row * (TSTEPS * 2) + t * 2 + 1] = sigf(v);
        }
      }
  }
}

// ---------------------------------------------------------------------------
extern "C" void kernel_launch(void* const* d_in, const int* in_sizes, int n_in,
                              void* d_out, int out_size, void* d_ws, size_t ws_size,
                              hipStream_t stream) {
  const float* latent = (const float*)d_in[0];
  const float* w_unp  = (const float*)d_in[2];
  const float* b_unp  = (const float*)d_in[3];
  const float* w_ih1  = (const float*)d_in[4];
  const float* w_hh1  = (const float*)d_in[5];
  const float* b_ih1  = (const float*)d_in[6];
  const float* b_hh1  = (const float*)d_in[7];
  const float* w_ih2  = (const float*)d_in[8];
  const float* w_hh2  = (const float*)d_in[9];
  const float* b_ih2  = (const float*)d_in[10];
  const float* b_hh2  = (const float*)d_in[11];
  const float* w_att  = (const float*)d_in[12];
  const float* b_att  = (const float*)d_in[13];
  const float* w_wid  = (const float*)d_in[14];
  const float* b_wid  = (const float*)d_in[15];
  const float* w_ang  = (const float*)d_in[16];
  const float* b_ang  = (const float*)d_in[17];
  float* out = (float*)d_out;

  char* ws = (char*)d_ws;
  __hip_bfloat16* W1T  = (__hip_bfloat16*)(ws + 0);          // 2048 x 2560 bf16
  __hip_bfloat16* W2T  = (__hip_bfloat16*)(ws + 10485760);   // 2048 x 1024
  __hip_bfloat16* WoT  = (__hip_bfloat16*)(ws + 14680064);   // 2176 x 512
  float* b1p           = (float*)(ws + 16908288);            // 2048
  float* b2p           = (float*)(ws + 16916480);            // 2048
  float* bo            = (float*)(ws + 16924672);            // 2176
  __hip_bfloat16* idea = (__hip_bfloat16*)(ws + 16933376);   // 1024 x 2048
  __hip_bfloat16* x_bf = (__hip_bfloat16*)(ws + 21127680);   // 1024 x 2560  [idea*att | h1]
  __hip_bfloat16* hcat = (__hip_bfloat16*)(ws + 26370560);   // 1024 x 1024  [h1 | h2]
  float* c1            = (float*)(ws + 28467712);            // 1024 x 512
  float* c2            = (float*)(ws + 30564864);            // 1024 x 512
  __hip_bfloat16* h2b  = (__hip_bfloat16*)(ws + 32662016);   // 1024 x 512

  conv_w1<<<2048, 256, 0, stream>>>(w_ih1, w_hh1, W1T);
  conv_w2<<<2048, 256, 0, stream>>>(w_ih2, w_hh2, W2T);
  conv_wo<<<2176, 256, 0, stream>>>(w_att, w_ang, w_wid, WoT);
  conv_b<<<9, 256, 0, stream>>>(b_ih1, b_hh1, b_ih2, b_hh2, b_att, b_ang, b_wid, b1p, b2p, bo);
  init_zero<<<1024, 256, 0, stream>>>(ws + 26370560, (char*)x_bf);
  idea_kernel<<<8192, 256, 0, stream>>>(latent, w_unp, b_unp, idea, x_bf);

  for (int t = 0; t < TSTEPS; ++t) {
    lstm_gemm<<<256, 256, 0, stream>>>((const char*)x_bf, (const char*)W1T,
                                       K1K, K1K / 64, b1p, c1, hcat, 1024);
    lstm_gemm<<<256, 256, 0, stream>>>((const char*)hcat, (const char*)W2T,
                                       K2K, K2K / 64, b2p, c2, h2b, 512);
    att_head<<<dim3(16, 17), 256, 0, stream>>>((const char*)h2b, (const char*)WoT,
                                               bo, idea, x_bf, hcat, h2b, out, t);
  }
}

// Round 4
// 5709.867 us; speedup vs baseline: 1.4365x; 1.1460x over previous
//
#include <hip/hip_runtime.h>
#include <hip/hip_bf16.h>
#include <cmath>

typedef __attribute__((ext_vector_type(8))) short bf16x8;
typedef __attribute__((ext_vector_type(4))) float f32x4;
typedef unsigned int u32;

#define DEVI __device__ __forceinline__

DEVI float sigf(float x) { return 1.0f / (1.0f + __expf(-x)); }

// async global->LDS, 16B per lane. LDS dest must be wave-uniform base (HW adds lane*16).
typedef const __attribute__((address_space(1))) u32* gas_t;
typedef __attribute__((address_space(3))) u32* las_t;
DEVI void g2l16(const void* g, void* l) {
  __builtin_amdgcn_global_load_lds((gas_t)g, (las_t)l, 16, 0, 0);
}

// ---- problem constants
#define BATCH 1024
#define CODE  2048
#define RNN   512
#define NG    2048      // 4*RNN
#define TSTEPS 128
#define K1K   2560      // CODE + RNN
#define K2K   1024      // RNN + RNN
#define K3K   512
#define NO    2176      // att cols padded: 2048 att + ang + wid + 126 pad (17 tiles of 128)

#define BUFSZ 24576     // one K-tile stage: A 8KB + B 16KB

// ---------------------------------------------------------------------------
// prologue kernels (run every launch; d_ws is re-poisoned before each launch)
// ---------------------------------------------------------------------------

__global__ void conv_w1(const float* __restrict__ w_ih1, const float* __restrict__ w_hh1,
                        __hip_bfloat16* __restrict__ W1T) {
  int np = blockIdx.x;                       // 0..2047, gate-interleaved: np = 4u+g
  int co = (np & 3) * RNN + (np >> 2);       // original gate column
  for (int k = threadIdx.x; k < K1K; k += 256) {
    float v = (k < CODE) ? w_ih1[(size_t)k * NG + co]
                         : w_hh1[(size_t)(k - CODE) * NG + co];
    W1T[(size_t)np * K1K + k] = __float2bfloat16(v);
  }
}

__global__ void conv_w2(const float* __restrict__ w_ih2, const float* __restrict__ w_hh2,
                        __hip_bfloat16* __restrict__ W2T) {
  int np = blockIdx.x;
  int co = (np & 3) * RNN + (np >> 2);
  for (int k = threadIdx.x; k < K2K; k += 256) {
    float v = (k < RNN) ? w_ih2[(size_t)k * NG + co]
                        : w_hh2[(size_t)(k - RNN) * NG + co];
    W2T[(size_t)np * K2K + k] = __float2bfloat16(v);
  }
}

__global__ void conv_wo(const float* __restrict__ w_att, const float* __restrict__ w_ang,
                        const float* __restrict__ w_wid, __hip_bfloat16* __restrict__ WoT) {
  int n = blockIdx.x;  // 0..2175
  for (int k = threadIdx.x; k < K3K; k += 256) {
    float v = 0.f;
    if (n < CODE) v = w_att[(size_t)k * CODE + n];
    else if (n == CODE) v = w_ang[k];
    else if (n == CODE + 1) v = w_wid[k];
    WoT[(size_t)n * K3K + k] = __float2bfloat16(v);
  }
}

__global__ void conv_b(const float* b_ih1, const float* b_hh1,
                       const float* b_ih2, const float* b_hh2,
                       const float* b_att, const float* b_ang, const float* b_wid,
                       float* b1p, float* b2p, float* bo) {
  int i = blockIdx.x * 256 + threadIdx.x;
  if (i < NG) {
    int co = (i & 3) * RNN + (i >> 2);
    b1p[i] = b_ih1[co] + b_hh1[co];
    b2p[i] = b_ih2[co] + b_hh2[co];
  }
  if (i < NO) {
    float v = 0.f;
    if (i < CODE) v = b_att[i];
    else if (i == CODE) v = b_ang[0];
    else if (i == CODE + 1) v = b_wid[0];
    bo[i] = v;
  }
}

// zero h_cat(2MB)+c1(2MB)+c2(2MB) contiguous + the h1 strip of x_bf
__global__ void init_zero(char* __restrict__ zb, char* __restrict__ xb) {
  int idx = blockIdx.x * 256 + threadIdx.x;       // 262144 threads
  f32x4 z = {0.f, 0.f, 0.f, 0.f};
  for (int i = idx; i < 393216; i += 262144) *(f32x4*)(zb + (size_t)i * 16) = z;
  for (int i = idx; i < 65536; i += 262144) {
    int row = i >> 6, j = i & 63;
    *(f32x4*)(xb + (size_t)row * (K1K * 2) + CODE * 2 + (size_t)j * 16) = z;
  }
}

// idea = tanh(latent @ w_unpack + b); also x_bf[:,0:2048] = idea (att0 = 1)
__global__ void idea_kernel(const float* __restrict__ latent, const float* __restrict__ w,
                            const float* __restrict__ b,
                            __hip_bfloat16* __restrict__ idea_bf,
                            __hip_bfloat16* __restrict__ x_bf) {
  int idx = blockIdx.x * 256 + threadIdx.x;       // 2M = 1024*2048
  int bi = idx >> 11, j = idx & 2047;
  const float* lr = latent + bi * 128;
  float s = b[j];
#pragma unroll 8
  for (int k = 0; k < 128; ++k) s = fmaf(lr[k], w[(size_t)k * CODE + j], s);
  __hip_bfloat16 h = __float2bfloat16(tanhf(s));
  idea_bf[idx] = h;
  x_bf[(size_t)bi * K1K + j] = h;
}

// ---- shared GEMM inner-loop fragments (8 waves, wave tile 32x32) -----------

#define STAGE(KO, DST)                                                        \
  _Pragma("unroll") for (int j = 0; j < 3; ++j)                               \
      g2l16(gp[j] + (KO), (DST) + ldsc[j]);

#define COMPUTE(SB)                                                           \
  __builtin_amdgcn_s_setprio(1);                                              \
  _Pragma("unroll") for (int kk = 0; kk < 2; ++kk) {                          \
    bf16x8 av[2], bv[2];                                                      \
    _Pragma("unroll") for (int fm = 0; fm < 2; ++fm)                          \
        av[fm] = *(const bf16x8*)((SB) + aoff[fm][kk]);                       \
    _Pragma("unroll") for (int fn = 0; fn < 2; ++fn)                          \
        bv[fn] = *(const bf16x8*)((SB) + boff[fn][kk]);                       \
    _Pragma("unroll") for (int fm = 0; fm < 2; ++fm)                          \
      _Pragma("unroll") for (int fn = 0; fn < 2; ++fn)                        \
        acc[fm][fn] = __builtin_amdgcn_mfma_f32_16x16x32_bf16(                \
            av[fm], bv[fn], acc[fm][fn], 0, 0, 0);                            \
  }                                                                           \
  __builtin_amdgcn_s_setprio(0);

#define WAITB(N)                                                              \
  asm volatile("s_waitcnt vmcnt(" #N ")" ::: "memory");                       \
  __builtin_amdgcn_s_barrier();                                               \
  asm volatile("" ::: "memory");

// ---------------------------------------------------------------------------
// Fused GEMM + LSTM cell. C = A[1024,K] @ BT[2048,K]^T, gate-interleaved N.
// BM=64, BN=128, BK=64; 512 threads = 8 waves (2 row x 4 col), wave tile 32x32
// -> 2 waves/SIMD for latency hiding (was 1).
// Staging: global_load_lds dwordx4, pre-swizzled SOURCE + linear LDS dest
// (involution: LDS[r*128+q] holds global (r, q ^ ((r&7)<<4))), 3 chunks/wave.
// Pipeline: 3 LDS buffers, prefetch depth 2, counted s_waitcnt vmcnt(3)
// (never 0 in steady state) + raw s_barrier (T3+T4); s_setprio around MFMA (T5).
// XCD swizzle: xcd=bid&7 owns n-tiles {2*xcd, 2*xcd+1} -> W slice L2-resident.
// ---------------------------------------------------------------------------
__global__ void __launch_bounds__(512, 2)
lstm_gemm(const char* __restrict__ Ab, const char* __restrict__ Bb,
          int K, int nk, const float* __restrict__ bias,
          float* __restrict__ c_state, __hip_bfloat16* __restrict__ h_out, int h_ld) {
  __shared__ char smem[3 * BUFSZ];  // 72KB; epilogue reuses 32KB as f32[64][128]
  const int tid = threadIdx.x;
  const int l = blockIdx.x;              // 256 blocks
  const int xcd = l & 7, bi = l >> 3;
  const int n0 = ((xcd << 1) | (bi & 1)) * 128;
  const int m0 = (bi >> 1) * 64;
  const int kb = K * 2;

  const int lane = tid & 63, wv = tid >> 6;   // wv 0..7
  const int rl = lane >> 3;              // row-in-8-group
  const int cswz = ((lane & 7) * 16) ^ (rl << 4);   // pre-swizzled source column

  // per-wave: 3 of the 24 1KB-chunks (A: 0..7 -> rows m0+.., B: 8..23 -> rows n0+..)
  const char* gp[3];
  int ldsc[3];
#pragma unroll
  for (int j = 0; j < 3; ++j) {
    int c = wv * 3 + j;
    int row = (c < 8) ? (m0 + c * 8 + rl) : (n0 + (c - 8) * 8 + rl);
    const char* base = (c < 8) ? Ab : Bb;
    gp[j] = base + (size_t)row * kb + cswz;
    ldsc[j] = c * 1024;
  }

  const int l16 = lane & 15, lg = lane >> 4;
  const int wr = wv & 1, wc = wv >> 1;        // 2 x 4 wave grid
  const int xm = (l16 & 7) << 4;

  int aoff[2][2], boff[2][2];
#pragma unroll
  for (int fm = 0; fm < 2; ++fm) {
    int r = wr * 32 + fm * 16 + l16;
#pragma unroll
    for (int kk = 0; kk < 2; ++kk) aoff[fm][kk] = r * 128 + ((kk * 64 + lg * 16) ^ xm);
  }
#pragma unroll
  for (int fn = 0; fn < 2; ++fn) {
    int r = wc * 32 + fn * 16 + l16;
#pragma unroll
    for (int kk = 0; kk < 2; ++kk) boff[fn][kk] = 8192 + r * 128 + ((kk * 64 + lg * 16) ^ xm);
  }

  f32x4 z4 = {0.f, 0.f, 0.f, 0.f};
  f32x4 acc[2][2];
#pragma unroll
  for (int a = 0; a < 2; ++a)
#pragma unroll
    for (int b = 0; b < 2; ++b) acc[a][b] = z4;

  // prologue: stage K-tiles 0 and 1
  STAGE(0, smem);
  STAGE(128, smem + BUFSZ);

  for (int kt = 0; kt < nk - 1; ++kt) {
    WAITB(3);                             // own tile-kt loads done; barrier publishes all
    if (kt + 2 < nk) {
      char* nb = smem + ((kt + 2) % 3) * BUFSZ;
      STAGE((size_t)(kt + 2) * 128, nb);
    }
    const char* sb = smem + (kt % 3) * BUFSZ;
    COMPUTE(sb);
  }
  WAITB(0);
  COMPUTE(smem + ((nk - 1) % 3) * BUFSZ);

  // ---- epilogue: recombine gates in LDS, apply LSTM cell
  __syncthreads();
  float* gsm = (float*)smem;  // [64][128]
#pragma unroll
  for (int fm = 0; fm < 2; ++fm)
#pragma unroll
    for (int fn = 0; fn < 2; ++fn) {
      int col = wc * 32 + fn * 16 + l16;
#pragma unroll
      for (int j = 0; j < 4; ++j) {
        int row = wr * 32 + fm * 16 + lg * 4 + j;  // C/D: col=lane&15, row=(lane>>4)*4+reg
        gsm[row * 128 + col] = acc[fm][fn][j];
      }
    }
  __syncthreads();
#pragma unroll
  for (int i = 0; i < 4; ++i) {
    int p = tid + i * 512;            // 64 rows x 32 units
    int unit = p & 31, row = p >> 5;
    f32x4 g = *(const f32x4*)(gsm + row * 128 + unit * 4);
    f32x4 bb = *(const f32x4*)(bias + n0 + unit * 4);
    float ig = sigf(g.x + bb.x);
    float fg = sigf(g.y + bb.y);
    float gg = tanhf(g.z + bb.z);
    float og = sigf(g.w + bb.w);
    int grow = m0 + row, gu = (n0 >> 2) + unit;
    float cold = c_state[grow * RNN + gu];
    float cn = fg * cold + ig * gg;
    c_state[grow * RNN + gu] = cn;
    h_out[(size_t)grow * h_ld + gu] = __float2bfloat16(og * tanhf(cn));
  }
}

// ---------------------------------------------------------------------------
// K3: att = sigmoid(h2 @ WoT^T) fused with x=idea*att, heads -> out[b,t,:],
// plus state copies (blockIdx.y==0 blocks):
//   x_bf[:,2048:2560] <- h_cat[:,0:512] (h1) ;  h_cat[:,512:1024] <- h2b
// BM=64, BN=128, grid 16x17, 512 threads; same pipelined core as lstm_gemm.
// ---------------------------------------------------------------------------
__global__ void __launch_bounds__(512, 2)
att_head(const char* __restrict__ Ab, const char* __restrict__ Bb,
         const float* __restrict__ bo,
         const __hip_bfloat16* __restrict__ idea_bf,
         __hip_bfloat16* __restrict__ x_bf,
         __hip_bfloat16* __restrict__ h_cat,
         const __hip_bfloat16* __restrict__ h2b,
         float* __restrict__ out, int t) {
  __shared__ char smem[3 * BUFSZ];
  const int tid = threadIdx.x;
  const int m0 = blockIdx.x * 64;
  const int n0 = blockIdx.y * 128;
  const int kb = K3K * 2;

  if (blockIdx.y == 0) {  // state copies for next step (regions disjoint from GEMM reads)
#pragma unroll
    for (int i = 0; i < 8; ++i) {
      int o = tid * 16 + i * 8192;  // 64 rows x 1024B
      int row = m0 + (o >> 10), cb = o & 1023;
      *(f32x4*)((char*)x_bf + (size_t)row * (K1K * 2) + CODE * 2 + cb) =
          *(const f32x4*)((const char*)h_cat + (size_t)row * (K2K * 2) + cb);
      *(f32x4*)((char*)h_cat + (size_t)row * (K2K * 2) + RNN * 2 + cb) =
          *(const f32x4*)((const char*)h2b + (size_t)row * (RNN * 2) + cb);
    }
  }

  const int lane = tid & 63, wv = tid >> 6;
  const int rl = lane >> 3;
  const int cswz = ((lane & 7) * 16) ^ (rl << 4);

  const char* gp[3];
  int ldsc[3];
#pragma unroll
  for (int j = 0; j < 3; ++j) {
    int c = wv * 3 + j;
    int row = (c < 8) ? (m0 + c * 8 + rl) : (n0 + (c - 8) * 8 + rl);
    const char* base = (c < 8) ? Ab : Bb;
    gp[j] = base + (size_t)row * kb + cswz;
    ldsc[j] = c * 1024;
  }

  const int l16 = lane & 15, lg = lane >> 4;
  const int wr = wv & 1, wc = wv >> 1;
  const int xm = (l16 & 7) << 4;

  int aoff[2][2], boff[2][2];
#pragma unroll
  for (int fm = 0; fm < 2; ++fm) {
    int r = wr * 32 + fm * 16 + l16;
#pragma unroll
    for (int kk = 0; kk < 2; ++kk) aoff[fm][kk] = r * 128 + ((kk * 64 + lg * 16) ^ xm);
  }
#pragma unroll
  for (int fn = 0; fn < 2; ++fn) {
    int r = wc * 32 + fn * 16 + l16;
#pragma unroll
    for (int kk = 0; kk < 2; ++kk) boff[fn][kk] = 8192 + r * 128 + ((kk * 64 + lg * 16) ^ xm);
  }

  f32x4 z4 = {0.f, 0.f, 0.f, 0.f};
  f32x4 acc[2][2];
#pragma unroll
  for (int a = 0; a < 2; ++a)
#pragma unroll
    for (int b = 0; b < 2; ++b) acc[a][b] = z4;

  const int nk = K3K / 64;  // 8
  STAGE(0, smem);
  STAGE(128, smem + BUFSZ);

  for (int kt = 0; kt < nk - 1; ++kt) {
    WAITB(3);
    if (kt + 2 < nk) {
      char* nb = smem + ((kt + 2) % 3) * BUFSZ;
      STAGE((size_t)(kt + 2) * 128, nb);
    }
    const char* sb = smem + (kt % 3) * BUFSZ;
    COMPUTE(sb);
  }
  WAITB(0);
  COMPUTE(smem + ((nk - 1) % 3) * BUFSZ);

  // per-lane epilogue
#pragma unroll
  for (int fn = 0; fn < 2; ++fn) {
    int col = n0 + wc * 32 + fn * 16 + l16;
    float bia = bo[col];
    bool is_att = col < CODE;
#pragma unroll
    for (int fm = 0; fm < 2; ++fm)
#pragma unroll
      for (int j = 0; j < 4; ++j) {
        int row = m0 + wr * 32 + fm * 16 + lg * 4 + j;
        float v = acc[fm][fn][j] + bia;
        if (is_att) {
          float a = sigf(v);
          float id = __bfloat162float(idea_bf[(size_t)row * CODE + col]);
          x_bf[(size_t)row * K1K + col] = __float2bfloat16(id * a);
        } else if (col == CODE) {
          out[row * (TSTEPS * 2) + t * 2] = tanhf(v);
        } else if (col == CODE + 1) {
          out[row * (TSTEPS * 2) + t * 2 + 1] = sigf(v);
        }
      }
  }
}

// ---------------------------------------------------------------------------
extern "C" void kernel_launch(void* const* d_in, const int* in_sizes, int n_in,
                              void* d_out, int out_size, void* d_ws, size_t ws_size,
                              hipStream_t stream) {
  const float* latent = (const float*)d_in[0];
  const float* w_unp  = (const float*)d_in[2];
  const float* b_unp  = (const float*)d_in[3];
  const float* w_ih1  = (const float*)d_in[4];
  const float* w_hh1  = (const float*)d_in[5];
  const float* b_ih1  = (const float*)d_in[6];
  const float* b_hh1  = (const float*)d_in[7];
  const float* w_ih2  = (const float*)d_in[8];
  const float* w_hh2  = (const float*)d_in[9];
  const float* b_ih2  = (const float*)d_in[10];
  const float* b_hh2  = (const float*)d_in[11];
  const float* w_att  = (const float*)d_in[12];
  const float* b_att  = (const float*)d_in[13];
  const float* w_wid  = (const float*)d_in[14];
  const float* b_wid  = (const float*)d_in[15];
  const float* w_ang  = (const float*)d_in[16];
  const float* b_ang  = (const float*)d_in[17];
  float* out = (float*)d_out;

  char* ws = (char*)d_ws;
  __hip_bfloat16* W1T  = (__hip_bfloat16*)(ws + 0);          // 2048 x 2560 bf16
  __hip_bfloat16* W2T  = (__hip_bfloat16*)(ws + 10485760);   // 2048 x 1024
  __hip_bfloat16* WoT  = (__hip_bfloat16*)(ws + 14680064);   // 2176 x 512
  float* b1p           = (float*)(ws + 16908288);            // 2048
  float* b2p           = (float*)(ws + 16916480);            // 2048
  float* bo            = (float*)(ws + 16924672);            // 2176
  __hip_bfloat16* idea = (__hip_bfloat16*)(ws + 16933376);   // 1024 x 2048
  __hip_bfloat16* x_bf = (__hip_bfloat16*)(ws + 21127680);   // 1024 x 2560  [idea*att | h1]
  __hip_bfloat16* hcat = (__hip_bfloat16*)(ws + 26370560);   // 1024 x 1024  [h1 | h2]
  float* c1            = (float*)(ws + 28467712);            // 1024 x 512
  float* c2            = (float*)(ws + 30564864);            // 1024 x 512
  __hip_bfloat16* h2b  = (__hip_bfloat16*)(ws + 32662016);   // 1024 x 512

  conv_w1<<<2048, 256, 0, stream>>>(w_ih1, w_hh1, W1T);
  conv_w2<<<2048, 256, 0, stream>>>(w_ih2, w_hh2, W2T);
  conv_wo<<<2176, 256, 0, stream>>>(w_att, w_ang, w_wid, WoT);
  conv_b<<<9, 256, 0, stream>>>(b_ih1, b_hh1, b_ih2, b_hh2, b_att, b_ang, b_wid, b1p, b2p, bo);
  init_zero<<<1024, 256, 0, stream>>>(ws + 26370560, (char*)x_bf);
  idea_kernel<<<8192, 256, 0, stream>>>(latent, w_unp, b_unp, idea, x_bf);

  for (int t = 0; t < TSTEPS; ++t) {
    lstm_gemm<<<256, 512, 0, stream>>>((const char*)x_bf, (const char*)W1T,
                                       K1K, K1K / 64, b1p, c1, hcat, 1024);
    lstm_gemm<<<256, 512, 0, stream>>>((const char*)hcat, (const char*)W2T,
                                       K2K, K2K / 64, b2p, c2, h2b, 512);
    att_head<<<dim3(16, 17), 512, 0, stream>>>((const char*)h2b, (const char*)WoT,
                                               bo, idea, x_bf, hcat, h2b, out, t);
  }
}